// Round 4
// baseline (341.197 us; speedup 1.0000x reference)
//
#include <hip/hip_runtime.h>

typedef unsigned short u16;
typedef __attribute__((ext_vector_type(8))) short bf16x8;  // 8 bf16 in 4 VGPRs
typedef __attribute__((ext_vector_type(4))) float f32x4;

constexpr int BATCH = 8192;
constexpr int UNITS = 1024;
constexpr int K2    = 2048;   // combined K  ([x | h_prev])
constexpr int N4    = 4096;   // 4*UNITS gate columns
// fragment-tile geometry: 16 rows x 32 k = 512 u16 = 1 KB per tile
constexpr int MT = BATCH / 16;   // 512 A m-tiles
constexpr int NT = N4 / 16;      // 256 B n-tiles
constexpr int KT = K2 / 32;      // 64 k-tiles

__device__ __forceinline__ u16 f2bf(float f) {
  unsigned u = __float_as_uint(f);
  u += 0x7fffu + ((u >> 16) & 1u);   // round-to-nearest-even
  return (u16)(u >> 16);
}

// ---------------------------------------------------------------------------
// Fused cast kernel — packs A and B directly into MFMA FRAGMENT layout.
// Tile(t, kt) is 1 KB: lane l = quad*16+c, elem j (16B/lane):
//   A: A[t*16 + c][kt*32 + quad*8 + j]        (A = [x | h_prev])
//   B: Bp[t*16 + c][kt*32 + quad*8 + j],  Bp[p][k] = orig[k][oc(p)]
//      oc(p) = jn*1024 + (p>>6)*16 + (p&15), jn = (p>>4)&3   (gate permute)
// Layout: Afrag[(kt*MT + mt)*512 u16], Bfrag[(kt*NT + nt)*512 u16].
//   blocks [0, 2048):    B pack (64 orig-cols x 64 k per block)
//   blocks [2048, 6144): A pack (64 rows x 64 k per block)
// ---------------------------------------------------------------------------
__global__ __launch_bounds__(256) void cast_fused_kernel(
    const float* __restrict__ x, const float* __restrict__ h,
    const float* __restrict__ W, const float* __restrict__ U,
    u16* __restrict__ Afrag, u16* __restrict__ Bfrag) {
  __shared__ float lds[64 * 69];
  const int tid = threadIdx.x;
  if (blockIdx.x < 2048) {
    // ---- B pack ----
    const int bid  = blockIdx.x;
    const int nblk = bid & 63;            // 64 orig-col tiles
    const int kblk = bid >> 6;            // 32 k tiles of 64
    const int n0   = nblk * 64;           // orig col base (one gate)
    const int k0   = kblk * 64;
    const int jn   = n0 >> 10;            // gate index
    const int q0   = (n0 & 1023) >> 4;    // base unit-group
    const float* src = (k0 < UNITS) ? (W + (size_t)k0 * N4)
                                    : (U + (size_t)(k0 - UNITS) * N4);
    // phase 1: coalesced read [64 k][64 n] into lds[k*69 + n]
    {
      const int kk  = tid >> 4;
      const int nn4 = (tid & 15) * 4;
#pragma unroll
      for (int r = 0; r < 4; ++r) {
        const int k = kk + r * 16;
        float4 v = *reinterpret_cast<const float4*>(&src[(size_t)k * N4 + n0 + nn4]);
        lds[k * 69 + nn4 + 0] = v.x;
        lds[k * 69 + nn4 + 1] = v.y;
        lds[k * 69 + nn4 + 2] = v.z;
        lds[k * 69 + nn4 + 3] = v.w;
      }
    }
    __syncthreads();
    // phase 2: 512 fragment-chunks of 16B; thread does ch = tid, tid+256
    {
#pragma unroll
      for (int half = 0; half < 2; ++half) {
        const int ch   = tid + half * 256;
        const int ktp  = ch >> 8;             // 0/1
        const int i    = (ch >> 6) & 3;       // n-tile within block
        const int ln   = ch & 63;
        const int q    = ln >> 4;
        const int cc   = ln & 15;
        const int rr   = i * 16 + cc;         // orig col - n0
        const int koff = ktp * 32 + q * 8;
        union { u16 s[8]; uint4 v; } o;
#pragma unroll
        for (int j = 0; j < 8; ++j) o.s[j] = f2bf(lds[(koff + j) * 69 + rr]);
        const int nt = (q0 + i) * 4 + jn;     // permuted p-tile index
        u16* dst = Bfrag + ((size_t)(kblk * 2 + ktp) * NT + nt) * 512 + ln * 8;
        *reinterpret_cast<uint4*>(dst) = o.v;
      }
    }
  } else {
    // ---- A pack ----
    const int bid  = blockIdx.x - 2048;
    const int rblk = bid >> 5;            // 128 row tiles of 64
    const int kblk = bid & 31;            // 32 k tiles of 64
    const int r0   = rblk * 64;
    const int k0   = kblk * 64;
    const float* src = (k0 < UNITS) ? (x + k0) : (h + (k0 - UNITS));
    // phase 1: coalesced read [64 r][64 k] into lds[r*65 + k]
    {
      const int rr  = tid >> 4;
      const int kq  = (tid & 15) * 4;
#pragma unroll
      for (int p = 0; p < 4; ++p) {
        const int row = rr + p * 16;
        float4 v = *reinterpret_cast<const float4*>(&src[(size_t)(r0 + row) * UNITS + kq]);
        lds[row * 65 + kq + 0] = v.x;
        lds[row * 65 + kq + 1] = v.y;
        lds[row * 65 + kq + 2] = v.z;
        lds[row * 65 + kq + 3] = v.w;
      }
    }
    __syncthreads();
    // phase 2: 512 fragment-chunks of 16B
    {
#pragma unroll
      for (int half = 0; half < 2; ++half) {
        const int ch   = tid + half * 256;
        const int ktp  = ch >> 8;
        const int mt_i = (ch >> 6) & 3;
        const int ln   = ch & 63;
        const int q    = ln >> 4;
        const int cc   = ln & 15;
        const int row  = mt_i * 16 + cc;
        const int koff = ktp * 32 + q * 8;
        union { u16 s[8]; uint4 v; } o;
#pragma unroll
        for (int j = 0; j < 8; ++j) o.s[j] = f2bf(lds[row * 65 + koff + j]);
        const int mt = rblk * 4 + mt_i;
        u16* dst = Afrag + ((size_t)(kblk * 2 + ktp) * MT + mt) * 512 + ln * 8;
        *reinterpret_cast<uint4*>(dst) = o.v;
      }
    }
  }
}

// ---------------------------------------------------------------------------
// FLAT fused GEMM + peephole LSTM: no LDS, no __syncthreads in the K-loop.
// Fragments load straight from pre-packed global into registers, depth-1
// register double-buffer -> compiler emits fine-grained vmcnt (never 0).
// Raw s_barrier every 2 kt keeps waves lockstepped for L1 frag sharing.
// ---------------------------------------------------------------------------
__global__ __launch_bounds__(256, 3) void lstm_gemm_flat(
    const u16* __restrict__ A, const u16* __restrict__ B,
    const float* __restrict__ bias, const float* __restrict__ c_prev,
    const float* __restrict__ pf, const float* __restrict__ pi,
    const float* __restrict__ po,
    float* __restrict__ out_h, float* __restrict__ out_c) {
  const int lid  = blockIdx.x;           // 2048; consecutive lids share nb
  const int nb   = lid >> 6;             // 0..31
  const int mb   = lid & 63;             // 0..63
  const int m0   = mb * 128;
  const int n0   = nb * 128;
  const int tid  = threadIdx.x;
  const int lane = tid & 63;
  const int wave = tid >> 6;
  const int quad = lane >> 4;
  const int c    = lane & 15;
  const int wm   = (wave >> 1) * 64;
  const int wn   = (wave & 1) * 64;

  const int mtb = (m0 + wm) >> 4;        // wave's base m-tile (4 consecutive)
  const int ntb = (n0 + wn) >> 4;        // wave's base n-tile (the 4 gates)
  const u16* pa = A + (size_t)mtb * 512 + lane * 8;
  const u16* pb = B + (size_t)ntb * 512 + lane * 8;
  constexpr size_t KA = (size_t)MT * 512;   // u16 per kt step of A
  constexpr size_t KB = (size_t)NT * 512;   // u16 per kt step of B

  f32x4  acc[4][4] = {};
  bf16x8 a_f[2][4], b_f[2][4];

#pragma unroll
  for (int j = 0; j < 4; ++j) {
    a_f[0][j] = *(const bf16x8*)(pa + j * 512);
    b_f[0][j] = *(const bf16x8*)(pb + j * 512);
  }

#pragma unroll 2
  for (int kt = 0; kt < KT; ++kt) {
    const int s = kt & 1;
    if (kt < KT - 1) {
      const u16* pan = pa + (size_t)(kt + 1) * KA;
      const u16* pbn = pb + (size_t)(kt + 1) * KB;
#pragma unroll
      for (int j = 0; j < 4; ++j) {
        a_f[s ^ 1][j] = *(const bf16x8*)(pan + j * 512);
        b_f[s ^ 1][j] = *(const bf16x8*)(pbn + j * 512);
      }
    }
#pragma unroll
    for (int jm = 0; jm < 4; ++jm)
#pragma unroll
      for (int jn = 0; jn < 4; ++jn)
        acc[jm][jn] = __builtin_amdgcn_mfma_f32_16x16x32_bf16(
            a_f[s][jm], b_f[s][jn], acc[jm][jn], 0, 0, 0);
    if (s == 1) __builtin_amdgcn_s_barrier();   // lockstep, no mem drain
  }

  // ---- fused peephole-LSTM epilogue -------------------------------------
  const int u = ((n0 + wn) >> 2) + c;
  const float bf_ = bias[u];
  const float bi_ = bias[UNITS + u];
  const float bc_ = bias[2 * UNITS + u];
  const float bo_ = bias[3 * UNITS + u];
  const float pfv = pf[u], piv = pi[u], pov = po[u];
  const int mbase = m0 + wm + quad * 4;
#pragma unroll
  for (int jm = 0; jm < 4; ++jm) {
#pragma unroll
    for (int r = 0; r < 4; ++r) {
      const int b = mbase + jm * 16 + r;
      const float cp = c_prev[(size_t)b * UNITS + u];
      const float zf = acc[jm][0][r] + bf_ + pfv * cp;
      const float zi = acc[jm][1][r] + bi_ + piv * cp;
      const float zc = acc[jm][2][r] + bc_;
      const float zo = acc[jm][3][r] + bo_;
      const float fg = 1.f / (1.f + __expf(-zf));
      const float ig = 1.f / (1.f + __expf(-zi));
      const float ct = 1.f - 2.f / (__expf(2.f * zc) + 1.f);   // tanh, NaN-safe
      const float cn = fg * cp + ig * ct;
      const float og = 1.f / (1.f + __expf(-(zo + pov * cn)));
      const float hn = og * (1.f - 2.f / (__expf(2.f * cn) + 1.f));
      out_h[(size_t)b * UNITS + u] = hn;
      out_c[(size_t)b * UNITS + u] = cn;
    }
  }
}

// ---------------------------------------------------------------------------
extern "C" void kernel_launch(void* const* d_in, const int* in_sizes, int n_in,
                              void* d_out, int out_size, void* d_ws, size_t ws_size,
                              hipStream_t stream) {
  const float* x      = (const float*)d_in[0];   // [8192,1024]
  const float* c_prev = (const float*)d_in[1];   // [8192,1024]
  const float* h_prev = (const float*)d_in[2];   // [8192,1024]
  const float* W      = (const float*)d_in[3];   // [1024,4096]
  const float* U      = (const float*)d_in[4];   // [1024,4096]
  const float* bias   = (const float*)d_in[5];   // [4096]
  const float* pf     = (const float*)d_in[6];   // [1024]
  const float* pi     = (const float*)d_in[7];
  const float* po     = (const float*)d_in[8];
  float* out_h = (float*)d_out;
  float* out_c = out_h + (size_t)BATCH * UNITS;

  u16* Abf = (u16*)d_ws;                           // 32 MB fragment-packed A
  u16* Bbf = Abf + (size_t)BATCH * K2;             // 16 MB fragment-packed B

  cast_fused_kernel<<<6144, 256, 0, stream>>>(x, h_prev, W, U, Abf, Bbf);
  lstm_gemm_flat<<<2048, 256, 0, stream>>>(
      Abf, Bbf, bias, c_prev, pf, pi, po, out_h, out_c);
}